// Round 8
// baseline (301.496 us; speedup 1.0000x reference)
//
#include <hip/hip_runtime.h>
#include <hip/hip_fp16.h>

typedef _Float16 f16;
typedef __attribute__((ext_vector_type(4))) _Float16 f16x4;
typedef __attribute__((ext_vector_type(8))) _Float16 f16x8;
typedef __attribute__((ext_vector_type(4))) float f32x4;
typedef __attribute__((ext_vector_type(16))) float f32x16;

#define MFMA_F16(a,b,c) __builtin_amdgcn_mfma_f32_16x16x32_f16((a),(b),(c),0,0,0)
#define MFMA32(a,b,c)   __builtin_amdgcn_mfma_f32_32x32x16_f16((a),(b),(c),0,0,0)

// async 16B/lane global->LDS DMA; global addr per-lane, LDS base wave-uniform
__device__ __forceinline__ void gl_lds16(const f16* g, f16* l) {
  __builtin_amdgcn_global_load_lds(
      (const __attribute__((address_space(1))) unsigned int*)g,
      (__attribute__((address_space(3))) unsigned int*)l, 16, 0, 0);
}

// Fragment-packed layout for 32x32x16 MFMA (per b,h): 16 T-tiles of 64 seq,
// each tile = 16 chunks of 512 f16 (chunk = 64 lanes x 8 f16, DMA-identity).
//  K/Q chunk (jt,ks), idx jt*8+ks: lane l: [row=T*64+jt*32+(l&31)][k=ks*16+(l>>5)*8+j]
//  V   chunk (ct,ks2), idx ct*4+ks2: lane l: [d=ct*32+(l&31)][kv=T*64+ks2*16+(l>>5)*8+j]

// ---------------------------------------------------------------------------
// Unified QKV projection. grid (128 X-tiles, 8 W-tiles, 3 {Q,K,V}).
// Register-prefetch of kt+1 tiles; Q/K transposed orientation (rows=hd),
// V normal (rows=bn2). Epilogues write the 32x32 fragment-packed layouts.
// ---------------------------------------------------------------------------
__global__ __launch_bounds__(256) void gemm_qkv(
    const float* __restrict__ x1, const float* __restrict__ x2,
    const float* __restrict__ wq, const float* __restrict__ wqb,
    const float* __restrict__ wk, const float* __restrict__ wkb,
    const float* __restrict__ wv, const float* __restrict__ wvb,
    f16* __restrict__ Qp, f16* __restrict__ Kp, f16* __restrict__ Vp,
    float qscale) {
  constexpr int LD = 72;
  __shared__ f16 As[128][LD];  // W-tile rows
  __shared__ f16 Bs[128][LD];  // X-tile rows
  const int z = blockIdx.z;
  const float* X    = (z == 0) ? x1 : x2;
  const float* W    = (z == 0) ? wq : (z == 1) ? wk : wv;
  const float* bias = (z == 0) ? wqb : (z == 1) ? wkb : wvb;
  f16* outp         = (z == 0) ? Qp : (z == 1) ? Kp : Vp;
  const float sc    = (z == 0) ? qscale : 1.0f;

  const int tid = threadIdx.x, lane = tid & 63, wid = tid >> 6;
  const int col = lane & 15, quad = lane >> 4;
  const int wm = (wid >> 1) * 64, wn = (wid & 1) * 64;
  const int n0x = blockIdx.x * 128;  // X rows (b*n2)
  const int m0w = blockIdx.y * 128;  // W rows (hd); h = blockIdx.y

  const int rr = tid >> 4, cc4 = tid & 15;

  f32x4 acc[4][4];
#pragma unroll
  for (int i = 0; i < 4; i++)
#pragma unroll
    for (int j = 0; j < 4; j++) acc[i][j] = (f32x4){0.f, 0.f, 0.f, 0.f};

  float4 wreg[8], xreg[8];
#pragma unroll
  for (int i = 0; i < 8; i++) {
    wreg[i] = *(const float4*)(W + (size_t)(m0w + rr + i * 16) * 256 + cc4 * 4);
    xreg[i] = *(const float4*)(X + (size_t)(n0x + rr + i * 16) * 256 + cc4 * 4);
  }

  for (int kt = 0; kt < 4; ++kt) {
#pragma unroll
    for (int i = 0; i < 8; i++) {
      float4 v = wreg[i];
      f16x4 hh; hh[0] = (f16)v.x; hh[1] = (f16)v.y; hh[2] = (f16)v.z; hh[3] = (f16)v.w;
      *(f16x4*)&As[rr + i * 16][cc4 * 4] = hh;
      v = xreg[i];
      f16x4 hg; hg[0] = (f16)v.x; hg[1] = (f16)v.y; hg[2] = (f16)v.z; hg[3] = (f16)v.w;
      *(f16x4*)&Bs[rr + i * 16][cc4 * 4] = hg;
    }
    __syncthreads();
    if (kt < 3) {
      const int k0 = (kt + 1) * 64;
#pragma unroll
      for (int i = 0; i < 8; i++) {
        wreg[i] = *(const float4*)(W + (size_t)(m0w + rr + i * 16) * 256 + k0 + cc4 * 4);
        xreg[i] = *(const float4*)(X + (size_t)(n0x + rr + i * 16) * 256 + k0 + cc4 * 4);
      }
    }
    const f16 (*Rs)[LD] = (z == 2) ? Bs : As;
    const f16 (*Cs)[LD] = (z == 2) ? As : Bs;
#pragma unroll
    for (int ks = 0; ks < 2; ks++) {
      f16x8 af[4], bf[4];
#pragma unroll
      for (int i = 0; i < 4; i++) af[i] = *(const f16x8*)&Rs[wm + i * 16 + col][ks * 32 + quad * 8];
#pragma unroll
      for (int j = 0; j < 4; j++) bf[j] = *(const f16x8*)&Cs[wn + j * 16 + col][ks * 32 + quad * 8];
#pragma unroll
      for (int i = 0; i < 4; i++)
#pragma unroll
        for (int j = 0; j < 4; j++) acc[i][j] = MFMA_F16(af[i], bf[j], acc[i][j]);
    }
    __syncthreads();
  }

  const int h = blockIdx.y;
  if (z < 2) {
    // rows = hd (k-runs over r), cols = bn2 -> K/Q chunk (jt,ks)
#pragma unroll
    for (int i = 0; i < 4; i++) {
      const int k0h = wm + i * 16 + quad * 4;  // k within head; k0h&7 in {0,4}
      float4 bq = *(const float4*)(bias + h * 128 + k0h);
      const int ks = k0h >> 4, jo = (k0h >> 3) & 1, off = k0h & 7;
#pragma unroll
      for (int j = 0; j < 4; j++) {
        const int bn2 = n0x + wn + j * 16 + col;
        const int b = bn2 >> 10, n2 = bn2 & 1023;
        const int T = n2 >> 6, jt = (n2 >> 5) & 1, lr = n2 & 31;
        f16x4 pk;
#pragma unroll
        for (int r = 0; r < 4; r++)
          pk[r] = (f16)((acc[i][j][r] + ((const float*)&bq)[r]) * sc);
        *(f16x4*)(outp + (size_t)(b * 8 + h) * 131072 + T * 8192 +
                  (jt * 8 + ks) * 512 + (jo * 32 + lr) * 8 + off) = pk;
      }
    }
  } else {
    // rows = bn2 (kv-runs over r), cols = hd -> V chunk (ct,ks2)
#pragma unroll
    for (int j = 0; j < 4; j++) {
      const int d = wn + j * 16 + col;  // d within head
      const float bv = bias[h * 128 + d];
      const int ct = d >> 5, lr = d & 31;
#pragma unroll
      for (int i = 0; i < 4; i++) {
        const int bn2 = n0x + wm + i * 16 + quad * 4;
        const int b = bn2 >> 10, n2 = bn2 & 1023;
        const int T = n2 >> 6, kv6 = n2 & 63;
        const int ks2 = kv6 >> 4, q2v = (kv6 >> 3) & 1, off = kv6 & 7;
        f16x4 pk;
#pragma unroll
        for (int r = 0; r < 4; r++) pk[r] = (f16)(acc[i][j][r] + bv);
        *(f16x4*)(outp + (size_t)(b * 8 + h) * 131072 + T * 8192 +
                  (ct * 4 + ks2) * 512 + (q2v * 32 + lr) * 8 + off) = pk;
      }
    }
  }
}

// ---------------------------------------------------------------------------
// Proj GEMM: out[16384,128] = A[16384,1024](f16) @ W[128,1024]^T + b, fp32.
// ---------------------------------------------------------------------------
__global__ __launch_bounds__(256) void gemm_proj(const f16* __restrict__ A,
                                                 const float* __restrict__ W,
                                                 const float* __restrict__ bias,
                                                 float* __restrict__ out) {
  constexpr int LD = 72;
  __shared__ f16 As[64][LD];
  __shared__ f16 Bs[64][LD];
  const int tid = threadIdx.x, lane = tid & 63, wid = tid >> 6;
  const int col = lane & 15, quad = lane >> 4;
  const int wm = (wid >> 1) * 32, wn = (wid & 1) * 32;
  const int m0 = blockIdx.x * 64, n0 = blockIdx.y * 64;

  f32x4 acc[2][2];
#pragma unroll
  for (int i = 0; i < 2; i++)
#pragma unroll
    for (int j = 0; j < 2; j++) acc[i][j] = (f32x4){0.f, 0.f, 0.f, 0.f};

  for (int kt = 0; kt < 16; ++kt) {
    const int k0 = kt * 64;
#pragma unroll
    for (int i = 0; i < 2; i++) {
      int f = i * 256 + tid;
      int r = f >> 3, ch = f & 7;
      *(f16x8*)&As[r][ch * 8] = *(const f16x8*)(A + (size_t)(m0 + r) * 1024 + k0 + ch * 8);
    }
#pragma unroll
    for (int i = 0; i < 4; i++) {
      int f = i * 256 + tid;
      int r = f >> 4, c4 = f & 15;
      float4 v = *(const float4*)(W + (size_t)(n0 + r) * 1024 + k0 + c4 * 4);
      f16x4 hh; hh[0] = (f16)v.x; hh[1] = (f16)v.y; hh[2] = (f16)v.z; hh[3] = (f16)v.w;
      *(f16x4*)&Bs[r][c4 * 4] = hh;
    }
    __syncthreads();
#pragma unroll
    for (int ks = 0; ks < 2; ks++) {
      f16x8 af[2], bf[2];
#pragma unroll
      for (int i = 0; i < 2; i++) af[i] = *(const f16x8*)&As[wm + i * 16 + col][ks * 32 + quad * 8];
#pragma unroll
      for (int j = 0; j < 2; j++) bf[j] = *(const f16x8*)&Bs[wn + j * 16 + col][ks * 32 + quad * 8];
#pragma unroll
      for (int i = 0; i < 2; i++)
#pragma unroll
        for (int j = 0; j < 2; j++) acc[i][j] = MFMA_F16(af[i], bf[j], acc[i][j]);
    }
    __syncthreads();
  }
#pragma unroll
  for (int j = 0; j < 2; j++) {
    const int c = n0 + wn + j * 16 + col;
    const float bv = bias[c];
#pragma unroll
    for (int i = 0; i < 2; i++) {
      const int r0 = m0 + wm + i * 16 + quad * 4;
#pragma unroll
      for (int r = 0; r < 4; r++)
        out[(size_t)(r0 + r) * 128 + c] = acc[i][j][r] + bv;
    }
  }
}

// ---------------------------------------------------------------------------
// Fused attention v7: 32x32x16 MFMA -> 2x FLOP per LDS byte (the v6 limiter
// was the DS pipe at ~88% busy). 4 waves x 32 q-rows, K/V double-buffered
// fragment chunks (coalesced DMA), Ps XOR-swizzled (b64 write / b128 read,
// phase-minimal banks). Per-wave per-iter: 36 b128 reads feed 32 big MFMAs.
// LDS 80KB -> 2 blocks/CU; waves_per_eu(2,2): 256-VGPR budget, demand ~190.
// ---------------------------------------------------------------------------
__global__ __launch_bounds__(256) __attribute__((amdgpu_waves_per_eu(2, 2)))
void attn_fused(const f16* __restrict__ Qp, const f16* __restrict__ Kp,
                const f16* __restrict__ Vp, const float* __restrict__ Bm,
                f16* __restrict__ O) {
  __shared__ f16 Ksl[2][8192];
  __shared__ f16 Vtl[2][8192];
  __shared__ f16 Ps[8192];
  const int tid = threadIdx.x, lane = tid & 63, wid = tid >> 6;
  const int lo5 = lane & 31, q2 = lane >> 5;
  const int id = blockIdx.x;
  const int mt = (id >> 3) & 7;
  const int bh = ((id >> 6) << 3) | (id & 7);  // 8 m-tiles of one bh per XCD
  const int b = bh >> 3, h = bh & 7;
  const int m0 = mt * 128;
  const int wm = wid * 32;  // wave's 32 q-rows

  const f16* Qb = Qp + (size_t)bh * 131072;
  const f16* Kb = Kp + (size_t)bh * 131072;
  const f16* Vb = Vp + (size_t)bh * 131072;

#define ISSUE(T, bufi)                                                       \
  {                                                                          \
    _Pragma("unroll") for (int j = 0; j < 4; j++) {                          \
      gl_lds16(Kb + (size_t)(T) * 8192 + (wid * 4 + j) * 512 + lane * 8,     \
               &Ksl[bufi][(wid * 4 + j) * 512]);                             \
      gl_lds16(Vb + (size_t)(T) * 8192 + (wid * 4 + j) * 512 + lane * 8,     \
               &Vtl[bufi][(wid * 4 + j) * 512]);                             \
    }                                                                        \
  }

  ISSUE(0, 0);
  ISSUE(1, 1);

  // Q fragments (B-operand, 32x32x16): wave's 32 rows, 8 k-chunks
  f16x8 qf[8];
  {
    const int m = m0 + wm;
    const int T = m >> 6, jt = (m >> 5) & 1;
#pragma unroll
    for (int ks = 0; ks < 8; ks++)
      qf[ks] = *(const f16x8*)(Qb + T * 8192 + (jt * 8 + ks) * 512 + lane * 8);
  }

  f32x16 oacc[4];
#pragma unroll
  for (int ct = 0; ct < 4; ct++)
#pragma unroll
    for (int r = 0; r < 16; r++) oacc[ct][r] = 0.f;
  float l = 0.f;  // row-sum for m = wm + lo5

  __syncthreads();

  for (int t = 0; t < 16; ++t) {
    const int buf = t & 1;
    const int n0 = t * 64;

    // bias tile (hidden under QK MFMAs): m = m0+wm+lo5, kv = jt*32+z*8+q2*4..
    float4 breg[2][4];
    {
      const float* Brow = Bm + (size_t)(m0 + wm + lo5) * 1024 + n0;
#pragma unroll
      for (int jt = 0; jt < 2; jt++)
#pragma unroll
        for (int zz = 0; zz < 4; zz++)
          breg[jt][zz] = *(const float4*)(Brow + jt * 32 + zz * 8 + q2 * 4);
    }

    // S^T = K Q^T : sT[jt] lane(lo5,q2): m=lo5, kv=jt*32+(r&3)+8*(r>>2)+4*q2
    f32x16 sT[2];
#pragma unroll
    for (int jt = 0; jt < 2; jt++)
#pragma unroll
      for (int r = 0; r < 16; r++) sT[jt][r] = 0.f;
#pragma unroll
    for (int ks = 0; ks < 8; ks++) {
      f16x8 kf0 = *(const f16x8*)&Ksl[buf][(0 * 8 + ks) * 512 + lane * 8];
      f16x8 kf1 = *(const f16x8*)&Ksl[buf][(1 * 8 + ks) * 512 + lane * 8];
      sT[0] = MFMA32(kf0, qf[ks], sT[0]);
      sT[1] = MFMA32(kf1, qf[ks], sT[1]);
    }

    // p = exp(s + B) (scale folded into Q'), row-sum, swizzled Ps b64 writes
    {
      const int m = wm + lo5;
#pragma unroll
      for (int jt = 0; jt < 2; jt++)
#pragma unroll
        for (int zz = 0; zz < 4; zz++) {
          const float* bv = (const float*)&breg[jt][zz];
          float p0 = __expf(sT[jt][zz * 4 + 0] + bv[0]);
          float p1 = __expf(sT[jt][zz * 4 + 1] + bv[1]);
          float p2 = __expf(sT[jt][zz * 4 + 2] + bv[2]);
          float p3 = __expf(sT[jt][zz * 4 + 3] + bv[3]);
          l += (p0 + p1) + (p2 + p3);
          f16x4 pk; pk[0] = (f16)p0; pk[1] = (f16)p1; pk[2] = (f16)p2; pk[3] = (f16)p3;
          const int g = (jt * 4 + zz) ^ (m & 7);
          *(f16x4*)&Ps[m * 64 + g * 8 + q2 * 4] = pk;
        }
    }

    // O += P V : A = P[m][kv] (swizzled b128), B = V chunks
#pragma unroll
    for (int ks2 = 0; ks2 < 4; ks2++) {
      const int m = wm + lo5;
      const int g = (ks2 * 2 + q2) ^ (m & 7);
      f16x8 pf = *(const f16x8*)&Ps[m * 64 + g * 8];
#pragma unroll
      for (int ct = 0; ct < 4; ct++) {
        f16x8 vf = *(const f16x8*)&Vtl[buf][(ct * 4 + ks2) * 512 + lane * 8];
        oacc[ct] = MFMA32(pf, vf, oacc[ct]);
      }
    }

    __syncthreads();  // buf free; DMA(t+1) drained (was in flight one iter)
    if (t + 2 < 16) ISSUE(t + 2, buf);
  }

  // finalize: l lives in lane lo5 for row wm+lo5 (reduce q2 halves)
  l += __shfl_xor(l, 32);
  // O store: lane holds cols d=ct*32+lo5, rows m=(r&3)+8*(r>>2)+4*q2
  f16* Ob = O + ((size_t)(b * 1024 + m0 + wm)) * 1024 + h * 128;
#pragma unroll
  for (int r = 0; r < 16; r++) {
    const int mloc = (r & 3) + 8 * (r >> 2) + 4 * q2;
    const float inv = 1.0f / __shfl(l, mloc);
#pragma unroll
    for (int ct = 0; ct < 4; ct++)
      Ob[(size_t)mloc * 1024 + ct * 32 + lo5] = (f16)(oacc[ct][r] * inv);
  }
}

extern "C" void kernel_launch(void* const* d_in, const int* in_sizes, int n_in,
                              void* d_out, int out_size, void* d_ws, size_t ws_size,
                              hipStream_t stream) {
  (void)in_sizes; (void)n_in; (void)out_size; (void)ws_size;
  const float* x1  = (const float*)d_in[0];
  const float* x2  = (const float*)d_in[1];
  const float* Bm  = (const float*)d_in[2];
  const float* wq  = (const float*)d_in[3];
  const float* wqb = (const float*)d_in[4];
  const float* wk  = (const float*)d_in[5];
  const float* wkb = (const float*)d_in[6];
  const float* wv  = (const float*)d_in[7];
  const float* wvb = (const float*)d_in[8];
  const float* pw  = (const float*)d_in[9];
  const float* pb  = (const float*)d_in[10];
  float* out = (float*)d_out;

  const size_t ELEMS = (size_t)16 * 1024 * 1024;
  f16* Qp = (f16*)d_ws;
  f16* Kp = Qp + ELEMS;
  f16* Vp = Kp + ELEMS;
  f16* Ow = Vp + ELEMS;

  const float scale = 0.0883883476483184f;  // 1/sqrt(128)
  gemm_qkv<<<dim3(128, 8, 3), dim3(256), 0, stream>>>(x1, x2, wq, wqb, wk, wkb,
                                                      wv, wvb, Qp, Kp, Vp, scale);
  attn_fused<<<dim3(1024), dim3(256), 0, stream>>>(Qp, Kp, Vp, Bm, Ow);
  gemm_proj<<<dim3(256, 2), dim3(256), 0, stream>>>(Ow, pw, pb, out);
}

// Round 9
// 279.031 us; speedup vs baseline: 1.0805x; 1.0805x over previous
//
#include <hip/hip_runtime.h>
#include <hip/hip_fp16.h>

typedef _Float16 f16;
typedef __attribute__((ext_vector_type(4))) _Float16 f16x4;
typedef __attribute__((ext_vector_type(8))) _Float16 f16x8;
typedef __attribute__((ext_vector_type(4))) float f32x4;

#define MFMA_F16(a,b,c) __builtin_amdgcn_mfma_f32_16x16x32_f16((a),(b),(c),0,0,0)

// async 16B/lane global->LDS DMA; global addr per-lane, LDS base wave-uniform
__device__ __forceinline__ void gl_lds16(const f16* g, f16* l) {
  __builtin_amdgcn_global_load_lds(
      (const __attribute__((address_space(1))) unsigned int*)g,
      (__attribute__((address_space(3))) unsigned int*)l, 16, 0, 0);
}

// ---------------------------------------------------------------------------
// Fragment-chunk packing (all DMA-ready, 1KB contiguous chunks):
//  input pack (x/W, [rows][256]): per 128-row tile, chunk (rt,ks8) idx rt*8+ks8
//    (rt 0..7, ks8 0..7): lane(q,c): [row=rt*16+c][k=ks8*32+q*8 .. +7]
//  Q/K workspace (per b,h; 16 T-tiles of 64 seq x 128 k): chunk (jt,ks) idx
//    jt*4+ks: lane(q,c): [seq=T*64+jt*16+c][k=ks*32+q*8]
//  V workspace: chunk (ct,ks2) idx ct*2+ks2: lane(q,c): [d=ct*16+c][kv=T*64+ks2*32+q*8]
// ---------------------------------------------------------------------------

// ---------------------------------------------------------------------------
// Pack pass: fp32 row-major -> f16 fragment-chunk tiles (coalesced in+out).
// Grid 280: 0..127 x1 tiles, 128..255 x2 tiles, 256..279 {wq,wk,wv} tiles.
// ---------------------------------------------------------------------------
__global__ __launch_bounds__(256) void conv_pack(
    const float* __restrict__ x1, const float* __restrict__ x2,
    const float* __restrict__ wq, const float* __restrict__ wk,
    const float* __restrict__ wv,
    f16* __restrict__ x1p, f16* __restrict__ x2p, f16* __restrict__ wp) {
  __shared__ f16 S[128][264];
  const int id = blockIdx.x, tid = threadIdx.x;
  const float* src;
  f16* dst;
  if (id < 128) {
    src = x1 + (size_t)id * 32768; dst = x1p + (size_t)id * 32768;
  } else if (id < 256) {
    src = x2 + (size_t)(id - 128) * 32768; dst = x2p + (size_t)(id - 128) * 32768;
  } else {
    const int wsel = (id - 256) >> 3, wt = (id - 256) & 7;
    const float* wsrc = (wsel == 0) ? wq : (wsel == 1) ? wk : wv;
    src = wsrc + (size_t)wt * 32768;
    dst = wp + (size_t)wsel * 262144 + (size_t)wt * 32768;
  }
#pragma unroll 8
  for (int i = 0; i < 32; i++) {
    int f = i * 256 + tid;           // 8192 float4s = 128 rows x 64
    int row = f >> 6, c4 = f & 63;
    float4 v = *(const float4*)(src + (size_t)row * 256 + c4 * 4);
    f16x4 hh; hh[0] = (f16)v.x; hh[1] = (f16)v.y; hh[2] = (f16)v.z; hh[3] = (f16)v.w;
    *(f16x4*)&S[row][c4 * 4] = hh;
  }
  __syncthreads();
#pragma unroll 8
  for (int i = 0; i < 16; i++) {
    int u = i * 256 + tid;           // 4096 b128 units
    int chunk = u >> 6, l2 = u & 63;
    int q = l2 >> 4, c = l2 & 15;
    int row = (chunk >> 3) * 16 + c, k = (chunk & 7) * 32 + q * 8;
    f16x8 v = *(const f16x8*)&S[row][k];
    *(f16x8*)(dst + (size_t)u * 8) = v;
  }
}

// ---------------------------------------------------------------------------
// QKV GEMM v4: pure-DMA staging (zero staging VALU). grid (128 xt, 8 h, 3 z).
// BM=128(hd) x BN=128(x) x BK=64, 4 K-iters, double-buffered, one barrier/iter,
// DMA one iter in flight. 512 thr = 8 waves (2 M-groups x 4 N-groups).
// z==2 (V) swaps operand roles so C rows = x (kv-runs) for the V layout.
// LDS 64KB -> 2 blocks/CU (16 waves/CU).
// ---------------------------------------------------------------------------
__global__ __launch_bounds__(512) __attribute__((amdgpu_waves_per_eu(4, 4)))
void gemm_qkv(const f16* __restrict__ x1p, const f16* __restrict__ x2p,
              const f16* __restrict__ wp,
              const float* __restrict__ wqb, const float* __restrict__ wkb,
              const float* __restrict__ wvb,
              f16* __restrict__ Qp, f16* __restrict__ Kp, f16* __restrict__ Vp,
              float qscale) {
  __shared__ f16 Wl[2][8192];
  __shared__ f16 Xl[2][8192];
  const int z = blockIdx.z;
  const f16* Xp = (z == 0) ? x1p : x2p;
  const float* bias = (z == 0) ? wqb : (z == 1) ? wkb : wvb;
  f16* outp = (z == 0) ? Qp : (z == 1) ? Kp : Vp;
  const float sc = (z == 0) ? qscale : 1.0f;

  const int tid = threadIdx.x, lane = tid & 63, wid = tid >> 6;
  const int col = lane & 15, quad = lane >> 4;
  const int xt = blockIdx.x, h = blockIdx.y;
  const int wr = wid >> 2, xc = wid & 3;  // wave M-group / N-group
  const f16* Xb = Xp + (size_t)xt * 32768;
  const f16* Wb = wp + (size_t)z * 262144 + (size_t)h * 32768;

  // stage K-iter T: chunks ks8 = T*2 + {0,1}; per wave 2 W + 2 X chunks
#define QISSUE(T, bufi)                                                   \
  {                                                                       \
    _Pragma("unroll") for (int j = 0; j < 2; j++) {                       \
      int lc = wid * 2 + j;                                               \
      int rt = lc >> 1, ksl = lc & 1;                                     \
      gl_lds16(Wb + (size_t)((rt * 8 + (T) * 2 + ksl) << 9) + lane * 8,   \
               &Wl[bufi][lc * 512]);                                      \
      gl_lds16(Xb + (size_t)((rt * 8 + (T) * 2 + ksl) << 9) + lane * 8,   \
               &Xl[bufi][lc * 512]);                                      \
    }                                                                     \
  }

  QISSUE(0, 0);
  QISSUE(1, 1);

  f32x4 acc[4][2];
#pragma unroll
  for (int i = 0; i < 4; i++)
#pragma unroll
    for (int j = 0; j < 2; j++) acc[i][j] = (f32x4){0.f, 0.f, 0.f, 0.f};

  __syncthreads();

  for (int t = 0; t < 4; ++t) {
    const int buf = t & 1;
    const f16* Ra = (z == 2) ? Xl[buf] : Wl[buf];  // A-operand (C rows)
    const f16* Cb = (z == 2) ? Wl[buf] : Xl[buf];  // B-operand (C cols)
#pragma unroll
    for (int ksl = 0; ksl < 2; ksl++) {
      f16x8 af[4], bf[2];
#pragma unroll
      for (int i = 0; i < 4; i++)
        af[i] = *(const f16x8*)&Ra[((wr * 4 + i) * 2 + ksl) * 512 + lane * 8];
#pragma unroll
      for (int j = 0; j < 2; j++)
        bf[j] = *(const f16x8*)&Cb[((xc * 2 + j) * 2 + ksl) * 512 + lane * 8];
#pragma unroll
      for (int i = 0; i < 4; i++)
#pragma unroll
        for (int j = 0; j < 2; j++) acc[i][j] = MFMA_F16(af[i], bf[j], acc[i][j]);
    }
    __syncthreads();
    if (t + 2 < 4) QISSUE(t + 2, buf);
  }

  if (z < 2) {
    // C rows = hd (k-runs over r), cols = bn2 -> Q/K packed chunks
#pragma unroll
    for (int i = 0; i < 4; i++) {
      const int k0h = wr * 64 + i * 16 + quad * 4;  // k within head; &7 in {0,4}
      float4 bq = *(const float4*)(bias + h * 128 + k0h);
      const int ks2 = k0h >> 5, q2 = (k0h >> 3) & 3, lo = k0h & 7;
#pragma unroll
      for (int j = 0; j < 2; j++) {
        const int bn2 = xt * 128 + xc * 32 + j * 16 + col;
        const int b = bn2 >> 10, n2 = bn2 & 1023;
        const int T = n2 >> 6, jt = (n2 >> 4) & 3, c2 = n2 & 15;
        f16x4 pk;
#pragma unroll
        for (int r = 0; r < 4; r++)
          pk[r] = (f16)((acc[i][j][r] + ((const float*)&bq)[r]) * sc);
        *(f16x4*)(outp + (size_t)(b * 8 + h) * 131072 + T * 8192 +
                  (jt * 4 + ks2) * 512 + (q2 * 16 + c2) * 8 + lo) = pk;
      }
    }
  } else {
    // C rows = bn2 (kv-runs over r), cols = hd -> V packed chunks
#pragma unroll
    for (int j = 0; j < 2; j++) {
      const int d = xc * 32 + j * 16 + col;  // d within head
      const float bv = bias[h * 128 + d];
      const int ct = d >> 4, cc = d & 15;
#pragma unroll
      for (int i = 0; i < 4; i++) {
        const int bn2 = xt * 128 + wr * 64 + i * 16 + quad * 4;
        const int b = bn2 >> 10, n2 = bn2 & 1023;
        const int T = n2 >> 6, kv6 = n2 & 63;
        const int ks2 = kv6 >> 5, qv = (kv6 >> 3) & 3, jj = kv6 & 7;
        f16x4 pk;
#pragma unroll
        for (int r = 0; r < 4; r++) pk[r] = (f16)(acc[i][j][r] + bv);
        *(f16x4*)(outp + (size_t)(b * 8 + h) * 131072 + T * 8192 +
                  (ct * 2 + ks2) * 512 + (qv * 16 + cc) * 8 + jj) = pk;
      }
    }
  }
}

// ---------------------------------------------------------------------------
// Proj GEMM: out[16384,128] = A[16384,1024](f16) @ W[128,1024]^T + b, fp32.
// BM=64, BN=64, grid (256,2) -> 2 blocks/CU (8 waves/CU).
// ---------------------------------------------------------------------------
__global__ __launch_bounds__(256) void gemm_proj(const f16* __restrict__ A,
                                                 const float* __restrict__ W,
                                                 const float* __restrict__ bias,
                                                 float* __restrict__ out) {
  constexpr int LD = 72;
  __shared__ f16 As[64][LD];
  __shared__ f16 Bs[64][LD];
  const int tid = threadIdx.x, lane = tid & 63, wid = tid >> 6;
  const int col = lane & 15, quad = lane >> 4;
  const int wm = (wid >> 1) * 32, wn = (wid & 1) * 32;
  const int m0 = blockIdx.x * 64, n0 = blockIdx.y * 64;

  f32x4 acc[2][2];
#pragma unroll
  for (int i = 0; i < 2; i++)
#pragma unroll
    for (int j = 0; j < 2; j++) acc[i][j] = (f32x4){0.f, 0.f, 0.f, 0.f};

  for (int kt = 0; kt < 16; ++kt) {
    const int k0 = kt * 64;
#pragma unroll
    for (int i = 0; i < 2; i++) {
      int f = i * 256 + tid;
      int r = f >> 3, ch = f & 7;
      *(f16x8*)&As[r][ch * 8] = *(const f16x8*)(A + (size_t)(m0 + r) * 1024 + k0 + ch * 8);
    }
#pragma unroll
    for (int i = 0; i < 4; i++) {
      int f = i * 256 + tid;
      int r = f >> 4, c4 = f & 15;
      float4 v = *(const float4*)(W + (size_t)(n0 + r) * 1024 + k0 + c4 * 4);
      f16x4 hh; hh[0] = (f16)v.x; hh[1] = (f16)v.y; hh[2] = (f16)v.z; hh[3] = (f16)v.w;
      *(f16x4*)&Bs[r][c4 * 4] = hh;
    }
    __syncthreads();
#pragma unroll
    for (int ks = 0; ks < 2; ks++) {
      f16x8 af[2], bf[2];
#pragma unroll
      for (int i = 0; i < 2; i++) af[i] = *(const f16x8*)&As[wm + i * 16 + col][ks * 32 + quad * 8];
#pragma unroll
      for (int j = 0; j < 2; j++) bf[j] = *(const f16x8*)&Bs[wn + j * 16 + col][ks * 32 + quad * 8];
#pragma unroll
      for (int i = 0; i < 2; i++)
#pragma unroll
        for (int j = 0; j < 2; j++) acc[i][j] = MFMA_F16(af[i], bf[j], acc[i][j]);
    }
    __syncthreads();
  }
#pragma unroll
  for (int j = 0; j < 2; j++) {
    const int c = n0 + wn + j * 16 + col;
    const float bv = bias[c];
#pragma unroll
    for (int i = 0; i < 2; i++) {
      const int r0 = m0 + wm + i * 16 + quad * 4;
#pragma unroll
      for (int r = 0; r < 4; r++)
        out[(size_t)(r0 + r) * 128 + c] = acc[i][j][r] + bv;
    }
  }
}

// ---------------------------------------------------------------------------
// Fused attention (R7 best: 110us): 512 thr = 8 waves x 16 q-rows,
// packed inputs, coalesced DMA, double-buffered K/V, one barrier/iter.
// ---------------------------------------------------------------------------
__global__ __launch_bounds__(512) __attribute__((amdgpu_waves_per_eu(4, 4)))
void attn_fused(const f16* __restrict__ Qp, const f16* __restrict__ Kp,
                const f16* __restrict__ Vp, const float* __restrict__ Bm,
                f16* __restrict__ O) {
  __shared__ f16 Ksl[2][8192];
  __shared__ f16 Vtl[2][8192];
  __shared__ f16 Ps[8192];
  const int tid = threadIdx.x, lane = tid & 63, wid = tid >> 6;  // wid 0..7
  const int col = lane & 15, quad = lane >> 4;
  const int id = blockIdx.x;
  const int mt = (id >> 3) & 7;
  const int bh = ((id >> 6) << 3) | (id & 7);  // 8 m-tiles of one bh per XCD
  const int b = bh >> 3, h = bh & 7;
  const int m0 = mt * 128;
  const int wm = wid * 16;  // wave's 16 q-rows

  const f16* Qb = Qp + (size_t)bh * 131072;
  const f16* Kb = Kp + (size_t)bh * 131072;
  const f16* Vb = Vp + (size_t)bh * 131072;

  // waves 0-3 stage K chunks, waves 4-7 stage V chunks (4 each)
#define AISSUE(T, bufi)                                                       \
  {                                                                           \
    if (wid < 4) {                                                            \
      _Pragma("unroll") for (int j = 0; j < 4; j++)                           \
          gl_lds16(Kb + (size_t)(T) * 8192 + (wid * 4 + j) * 512 + lane * 8,  \
                   &Ksl[bufi][(wid * 4 + j) * 512]);                          \
    } else {                                                                  \
      _Pragma("unroll") for (int j = 0; j < 4; j++)                           \
          gl_lds16(Vb + (size_t)(T) * 8192 + ((wid - 4) * 4 + j) * 512 + lane * 8, \
                   &Vtl[bufi][((wid - 4) * 4 + j) * 512]);                    \
    }                                                                         \
  }

  AISSUE(0, 0);
  AISSUE(1, 1);

  f16x8 qf[4];
  {
    const int m = m0 + wm;
    const int T = m >> 6, jt2 = (m >> 4) & 3;
#pragma unroll
    for (int ks = 0; ks < 4; ks++)
      qf[ks] = *(const f16x8*)(Qb + T * 8192 + (jt2 * 4 + ks) * 512 + lane * 8);
  }

  f32x4 oacc[8];
  float l = 0.f;
#pragma unroll
  for (int ct = 0; ct < 8; ct++) oacc[ct] = (f32x4){0.f, 0.f, 0.f, 0.f};

  __syncthreads();

  for (int t = 0; t < 16; ++t) {
    const int buf = t & 1;
    const int n0 = t * 64;

    float4 breg[4];
    {
      const float* Brow = Bm + (size_t)(m0 + wm + col) * 1024 + n0;
#pragma unroll
      for (int jt = 0; jt < 4; jt++)
        breg[jt] = *(const float4*)(Brow + jt * 16 + quad * 4);
    }

    f32x4 s[4];
#pragma unroll
    for (int jt = 0; jt < 4; jt++) s[jt] = (f32x4){0.f, 0.f, 0.f, 0.f};
#pragma unroll
    for (int ks = 0; ks < 4; ks++) {
      f16x8 kf[4];
#pragma unroll
      for (int jt = 0; jt < 4; jt++)
        kf[jt] = *(const f16x8*)&Ksl[buf][(jt * 4 + ks) * 512 + lane * 8];
#pragma unroll
      for (int jt = 0; jt < 4; jt++) s[jt] = MFMA_F16(kf[jt], qf[ks], s[jt]);
    }

    {
      const int m = wm + col;
#pragma unroll
      for (int jt = 0; jt < 4; jt++) {
        const float* bv = (const float*)&breg[jt];
        float p0 = __expf(s[jt][0] + bv[0]);
        float p1 = __expf(s[jt][1] + bv[1]);
        float p2 = __expf(s[jt][2] + bv[2]);
        float p3 = __expf(s[jt][3] + bv[3]);
        l += (p0 + p1) + (p2 + p3);
        f16x4 pk; pk[0] = (f16)p0; pk[1] = (f16)p1; pk[2] = (f16)p2; pk[3] = (f16)p3;
        const int g = (jt * 2 + (quad >> 1)) ^ (col & 7);
        *(f16x4*)&Ps[m * 64 + g * 8 + (quad & 1) * 4] = pk;
      }
    }

#pragma unroll
    for (int ks = 0; ks < 2; ks++) {
      const int m = wm + col;
      const int g = (ks * 4 + quad) ^ (col & 7);
      f16x8 pf = *(const f16x8*)&Ps[m * 64 + g * 8];
#pragma unroll
      for (int ct = 0; ct < 8; ct++) {
        f16x8 vf = *(const f16x8*)&Vtl[buf][(ct * 2 + ks) * 512 + lane * 8];
        oacc[ct] = MFMA_F16(pf, vf, oacc[ct]);
      }
    }

    __syncthreads();
    if (t + 2 < 16) AISSUE(t + 2, buf);
  }

  l += __shfl_xor(l, 16);
  l += __shfl_xor(l, 32);
  f16* Ob = O + ((size_t)(b * 1024 + m0 + wm)) * 1024 + h * 128;
#pragma unroll
  for (int r = 0; r < 4; r++) {
    const float lv = __shfl(l, (lane & 48) | (quad * 4 + r));
    const float inv = 1.0f / lv;
#pragma unroll
    for (int ct = 0; ct < 8; ct++)
      Ob[(size_t)(quad * 4 + r) * 1024 + ct * 16 + col] = (f16)(oacc[ct][r] * inv);
  }
}

extern "C" void kernel_launch(void* const* d_in, const int* in_sizes, int n_in,
                              void* d_out, int out_size, void* d_ws, size_t ws_size,
                              hipStream_t stream) {
  (void)in_sizes; (void)n_in; (void)out_size; (void)ws_size;
  const float* x1  = (const float*)d_in[0];
  const float* x2  = (const float*)d_in[1];
  const float* Bm  = (const float*)d_in[2];
  const float* wq  = (const float*)d_in[3];
  const float* wqb = (const float*)d_in[4];
  const float* wk  = (const float*)d_in[5];
  const float* wkb = (const float*)d_in[6];
  const float* wv  = (const float*)d_in[7];
  const float* wvb = (const float*)d_in[8];
  const float* pw  = (const float*)d_in[9];
  const float* pb  = (const float*)d_in[10];
  float* out = (float*)d_out;

  const size_t MiB = 1024 * 1024;
  f16* Qp  = (f16*)d_ws;                            // 0..32 MiB
  f16* Kp  = (f16*)((char*)d_ws + 32 * MiB);        // 32..64
  f16* Vp  = (f16*)((char*)d_ws + 64 * MiB);        // 64..96
  f16* Ow  = (f16*)((char*)d_ws + 96 * MiB);        // 96..128 (attn output)
  // packed inputs: alive only conv->qkv, then overlaid by Ow
  f16* x1p = (f16*)((char*)d_ws + 96 * MiB);        // 8 MiB
  f16* x2p = (f16*)((char*)d_ws + 104 * MiB);       // 8 MiB
  f16* wp  = (f16*)((char*)d_ws + 112 * MiB);       // 1.5 MiB

  const float scale = 0.0883883476483184f;  // 1/sqrt(128)
  conv_pack<<<dim3(280), dim3(256), 0, stream>>>(x1, x2, wq, wk, wv, x1p, x2p, wp);
  gemm_qkv<<<dim3(128, 8, 3), dim3(512), 0, stream>>>(x1p, x2p, wp, wqb, wkb, wvb,
                                                      Qp, Kp, Vp, scale);
  attn_fused<<<dim3(1024), dim3(512), 0, stream>>>(Qp, Kp, Vp, Bm, Ow);
  gemm_proj<<<dim3(256, 2), dim3(256), 0, stream>>>(Ow, pw, pb, out);
}